// Round 1
// baseline (324.897 us; speedup 1.0000x reference)
//
#include <hip/hip_runtime.h>
#include <math.h>

#define BN 8
#define DEMB 128
#define NP 3072
#define ROWS 64      // query rows per block
#define MT 64        // m-tile per wave
#define DC 32        // d-chunk staged in LDS
#define SPLITS 2     // m splits across blockIdx.y
#define NSETS (SPLITS*4)   // total partial sets per row (y-splits x 4 waves)

#define PART_FLOATS (NSETS*BN*NP*5)

// ------------------------------------------------------------------
// K1: fused scores+softmax+PV (flash style), partial outputs per m-range
// ------------------------------------------------------------------
__global__ __launch_bounds__(256) void k_attn(const float* __restrict__ qe,
                                              const float* __restrict__ te,
                                              const float* __restrict__ tgt,
                                              float* __restrict__ part)
{
    __shared__ float q_lds[DC][ROWS];
    __shared__ float e_lds[4][DC][MT];

    const int b    = blockIdx.z;
    const int n0   = blockIdx.x * ROWS;
    const int wid  = threadIdx.x >> 6;
    const int lane = threadIdx.x & 63;
    const int li   = lane >> 3;
    const int lj   = lane & 7;

    const int m_base  = blockIdx.y * (NP / SPLITS) + wid * (NP / SPLITS / 4);
    const int MTILES  = NP / SPLITS / 4 / MT;   // 6

    const float* qp = qe  + (size_t)b * DEMB * NP;
    const float* ep = te  + (size_t)b * DEMB * NP;
    const float* tp = tgt + (size_t)b * 3 * NP;

    float m_run[8], l_run[8], o[8][3];
#pragma unroll
    for (int i = 0; i < 8; ++i) {
        m_run[i] = -3.0e38f;
        l_run[i] = 0.f;
        o[i][0] = o[i][1] = o[i][2] = 0.f;
    }

    for (int mt = 0; mt < MTILES; ++mt) {
        const int m0 = m_base + mt * MT;
        float s[8][8];
#pragma unroll
        for (int i = 0; i < 8; ++i)
#pragma unroll
            for (int j = 0; j < 8; ++j) s[i][j] = 0.f;

        for (int dc = 0; dc < DEMB / DC; ++dc) {
            __syncthreads();   // protect LDS from overwrite while in use
            // stage q chunk [DC][ROWS] cooperatively (coalesced over n)
#pragma unroll
            for (int k = 0; k < (DC * ROWS) / 256; ++k) {
                int idx = threadIdx.x + k * 256;
                int dd  = idx >> 6;
                int col = idx & 63;
                q_lds[dd][col] = qp[(size_t)(dc * DC + dd) * NP + n0 + col];
            }
            // stage e chunk per wave [DC][MT] (coalesced over m)
#pragma unroll 8
            for (int dd = 0; dd < DC; ++dd) {
                e_lds[wid][dd][lane] = ep[(size_t)(dc * DC + dd) * NP + m0 + lane];
            }
            __syncthreads();
#pragma unroll 8
            for (int d = 0; d < DC; ++d) {
                const float4 qa = *(const float4*)&q_lds[d][li * 8];
                const float4 qb = *(const float4*)&q_lds[d][li * 8 + 4];
                const float4 ea = *(const float4*)&e_lds[wid][d][lj * 8];
                const float4 eb = *(const float4*)&e_lds[wid][d][lj * 8 + 4];
                const float qv[8] = {qa.x, qa.y, qa.z, qa.w, qb.x, qb.y, qb.z, qb.w};
                const float ev[8] = {ea.x, ea.y, ea.z, ea.w, eb.x, eb.y, eb.z, eb.w};
#pragma unroll
                for (int i = 0; i < 8; ++i)
#pragma unroll
                    for (int j = 0; j < 8; ++j)
                        s[i][j] += qv[i] * ev[j];
            }
        }

        // online softmax update for this m-tile
        const float scale = 0.08838834764831845f;  // 1/sqrt(128)
        float tv[3][8];
#pragma unroll
        for (int c = 0; c < 3; ++c)
#pragma unroll
            for (int j = 0; j < 8; ++j)
                tv[c][j] = tp[c * NP + m0 + lj * 8 + j];

#pragma unroll
        for (int i = 0; i < 8; ++i) {
            float mx = s[i][0] * scale;
#pragma unroll
            for (int j = 1; j < 8; ++j) mx = fmaxf(mx, s[i][j] * scale);
            mx = fmaxf(mx, __shfl_xor(mx, 1));
            mx = fmaxf(mx, __shfl_xor(mx, 2));
            mx = fmaxf(mx, __shfl_xor(mx, 4));
            const float mnew = fmaxf(m_run[i], mx);
            const float cf = __expf(m_run[i] - mnew);
            m_run[i] = mnew;
            l_run[i] *= cf;
            o[i][0] *= cf; o[i][1] *= cf; o[i][2] *= cf;
#pragma unroll
            for (int j = 0; j < 8; ++j) {
                const float p = __expf(s[i][j] * scale - mnew);
                l_run[i] += p;
                o[i][0] += p * tv[0][j];
                o[i][1] += p * tv[1][j];
                o[i][2] += p * tv[2][j];
            }
        }
    }

    // cross-lane (lj) reduction and partial write
    const int set = blockIdx.y * 4 + wid;
#pragma unroll
    for (int i = 0; i < 8; ++i) {
#pragma unroll
        for (int mask = 1; mask < 8; mask <<= 1) {
            l_run[i] += __shfl_xor(l_run[i], mask);
            o[i][0]  += __shfl_xor(o[i][0], mask);
            o[i][1]  += __shfl_xor(o[i][1], mask);
            o[i][2]  += __shfl_xor(o[i][2], mask);
        }
        if (lj == 0) {
            const int n = n0 + li * 8 + i;
            float* pp = part + (((size_t)set * BN + b) * NP + n) * 5;
            pp[0] = o[i][0]; pp[1] = o[i][1]; pp[2] = o[i][2];
            pp[3] = l_run[i]; pp[4] = m_run[i];
        }
    }
}

// ------------------------------------------------------------------
// K2: combine flash partials -> src_corr [B][3][N]
// ------------------------------------------------------------------
__global__ __launch_bounds__(256) void k_combine(const float* __restrict__ part,
                                                 float* __restrict__ corr)
{
    const int idx = blockIdx.x * 256 + threadIdx.x;
    if (idx >= BN * NP) return;
    const int b = idx / NP;
    const int n = idx % NP;
    float M = -3.0e38f;
#pragma unroll
    for (int s = 0; s < NSETS; ++s)
        M = fmaxf(M, part[(((size_t)s * BN + b) * NP + n) * 5 + 4]);
    float L = 0.f, o0 = 0.f, o1 = 0.f, o2 = 0.f;
#pragma unroll
    for (int s = 0; s < NSETS; ++s) {
        const float* pp = part + (((size_t)s * BN + b) * NP + n) * 5;
        const float w = __expf(pp[4] - M);
        o0 += pp[0] * w; o1 += pp[1] * w; o2 += pp[2] * w; L += pp[3] * w;
    }
    const float inv = 1.f / L;
    corr[((size_t)b * 3 + 0) * NP + n] = o0 * inv;
    corr[((size_t)b * 3 + 1) * NP + n] = o1 * inv;
    corr[((size_t)b * 3 + 2) * NP + n] = o2 * inv;
}

// ------------------------------------------------------------------
// K3: per-batch reduction (means, H) + 3x3 SVD (fp64 Jacobi) + outputs
// ------------------------------------------------------------------
__global__ __launch_bounds__(256) void k_final(const float* __restrict__ src,
                                               const float* __restrict__ corr,
                                               float* __restrict__ out)
{
    const int b = blockIdx.x;
    const float* sp = src  + (size_t)b * 3 * NP;
    const float* cp = corr + (size_t)b * 3 * NP;

    double acc[15];
#pragma unroll
    for (int v = 0; v < 15; ++v) acc[v] = 0.0;

    for (int n = threadIdx.x; n < NP; n += 256) {
        const double x0 = sp[n], x1 = sp[NP + n], x2 = sp[2 * NP + n];
        const double y0 = cp[n], y1 = cp[NP + n], y2 = cp[2 * NP + n];
        acc[0] += x0; acc[1] += x1; acc[2] += x2;
        acc[3] += y0; acc[4] += y1; acc[5] += y2;
        acc[6]  += x0 * y0; acc[7]  += x0 * y1; acc[8]  += x0 * y2;
        acc[9]  += x1 * y0; acc[10] += x1 * y1; acc[11] += x1 * y2;
        acc[12] += x2 * y0; acc[13] += x2 * y1; acc[14] += x2 * y2;
    }

    const int wid = threadIdx.x >> 6, lane = threadIdx.x & 63;
#pragma unroll
    for (int v = 0; v < 15; ++v)
#pragma unroll
        for (int mask = 32; mask >= 1; mask >>= 1)
            acc[v] += __shfl_xor(acc[v], mask);

    __shared__ double red[4][15];
    if (lane == 0) {
#pragma unroll
        for (int v = 0; v < 15; ++v) red[wid][v] = acc[v];
    }
    __syncthreads();
    if (threadIdx.x != 0) return;

    double t15[15];
#pragma unroll
    for (int v = 0; v < 15; ++v)
        t15[v] = red[0][v] + red[1][v] + red[2][v] + red[3][v];

    const double invN = 1.0 / NP;
    const double mx[3] = {t15[0] * invN, t15[1] * invN, t15[2] * invN};
    const double my[3] = {t15[3] * invN, t15[4] * invN, t15[5] * invN};
    double H[3][3];
#pragma unroll
    for (int i = 0; i < 3; ++i)
#pragma unroll
        for (int j = 0; j < 3; ++j)
            H[i][j] = t15[6 + i * 3 + j] - (double)NP * mx[i] * my[j];

    // A = H^T H (symmetric), Jacobi eigendecomposition -> V, lambda
    double A[3][3], V[3][3];
#pragma unroll
    for (int i = 0; i < 3; ++i)
#pragma unroll
        for (int j = 0; j < 3; ++j) {
            A[i][j] = H[0][i] * H[0][j] + H[1][i] * H[1][j] + H[2][i] * H[2][j];
            V[i][j] = (i == j) ? 1.0 : 0.0;
        }

    for (int sweep = 0; sweep < 30; ++sweep) {
        const int pqs[3][2] = {{0, 1}, {0, 2}, {1, 2}};
        for (int k = 0; k < 3; ++k) {
            const int p = pqs[k][0], q = pqs[k][1];
            const double apq = A[p][q];
            if (fabs(apq) < 1e-300) continue;
            const double theta = (A[q][q] - A[p][p]) / (2.0 * apq);
            const double tj = (theta >= 0 ? 1.0 : -1.0) /
                              (fabs(theta) + sqrt(theta * theta + 1.0));
            const double c = 1.0 / sqrt(tj * tj + 1.0);
            const double s = tj * c;
            for (int i = 0; i < 3; ++i) {
                const double aip = A[i][p], aiq = A[i][q];
                A[i][p] = c * aip - s * aiq;
                A[i][q] = s * aip + c * aiq;
            }
            for (int i = 0; i < 3; ++i) {
                const double api = A[p][i], aqi = A[q][i];
                A[p][i] = c * api - s * aqi;
                A[q][i] = s * api + c * aqi;
            }
            for (int i = 0; i < 3; ++i) {
                const double vip = V[i][p], viq = V[i][q];
                V[i][p] = c * vip - s * viq;
                V[i][q] = s * vip + c * viq;
            }
        }
    }

    // sort eigenvalues descending, build Vs, sv, U
    double lam[3] = {A[0][0], A[1][1], A[2][2]};
    int ord[3] = {0, 1, 2};
    for (int i = 0; i < 2; ++i)
        for (int j = i + 1; j < 3; ++j)
            if (lam[ord[j]] > lam[ord[i]]) { int t = ord[i]; ord[i] = ord[j]; ord[j] = t; }

    double Vs[3][3], sv[3];
    for (int j = 0; j < 3; ++j) {
        sv[j] = sqrt(fmax(lam[ord[j]], 0.0));
        for (int i = 0; i < 3; ++i) Vs[i][j] = V[i][ord[j]];
    }
    double U[3][3];
    for (int j = 0; j < 3; ++j) {
        const double h0 = H[0][0] * Vs[0][j] + H[0][1] * Vs[1][j] + H[0][2] * Vs[2][j];
        const double h1 = H[1][0] * Vs[0][j] + H[1][1] * Vs[1][j] + H[1][2] * Vs[2][j];
        const double h2 = H[2][0] * Vs[0][j] + H[2][1] * Vs[1][j] + H[2][2] * Vs[2][j];
        const double inv = 1.0 / fmax(sv[j], 1e-300);
        U[0][j] = h0 * inv; U[1][j] = h1 * inv; U[2][j] = h2 * inv;
    }

    double R[3][3];
    for (int i = 0; i < 3; ++i)
        for (int j = 0; j < 3; ++j)
            R[i][j] = Vs[i][0] * U[j][0] + Vs[i][1] * U[j][1] + Vs[i][2] * U[j][2];
    const double det =
        R[0][0] * (R[1][1] * R[2][2] - R[1][2] * R[2][1]) -
        R[0][1] * (R[1][0] * R[2][2] - R[1][2] * R[2][0]) +
        R[0][2] * (R[1][0] * R[2][1] - R[1][1] * R[2][0]);
    if (det < 0.0) {
        Vs[0][2] = -Vs[0][2]; Vs[1][2] = -Vs[1][2]; Vs[2][2] = -Vs[2][2];
        for (int i = 0; i < 3; ++i)
            for (int j = 0; j < 3; ++j)
                R[i][j] = Vs[i][0] * U[j][0] + Vs[i][1] * U[j][1] + Vs[i][2] * U[j][2];
    }

    double tvec[3];
    for (int i = 0; i < 3; ++i)
        tvec[i] = -(R[i][0] * mx[0] + R[i][1] * mx[1] + R[i][2] * mx[2]) + my[i];

    const double ex = atan2(R[2][1], R[2][2]);
    const double syv = sqrt(R[0][0] * R[0][0] + R[1][0] * R[1][0]);
    const double ey = atan2(-R[2][0], syv);
    const double ez = atan2(R[1][0], R[0][0]);

    for (int i = 0; i < 3; ++i)
        for (int j = 0; j < 3; ++j)
            out[b * 9 + i * 3 + j] = (float)R[i][j];
    out[72 + b * 3 + 0] = (float)tvec[0];
    out[72 + b * 3 + 1] = (float)tvec[1];
    out[72 + b * 3 + 2] = (float)tvec[2];
    out[96 + b * 3 + 0] = (float)ex;
    out[96 + b * 3 + 1] = (float)ey;
    out[96 + b * 3 + 2] = (float)ez;
}

// ------------------------------------------------------------------
extern "C" void kernel_launch(void* const* d_in, const int* in_sizes, int n_in,
                              void* d_out, int out_size, void* d_ws, size_t ws_size,
                              hipStream_t stream) {
    const float* qe  = (const float*)d_in[0];  // src_embedding [B,128,N]
    const float* te  = (const float*)d_in[1];  // tgt_embedding [B,128,N]
    const float* src = (const float*)d_in[2];  // src [B,3,N]
    const float* tgt = (const float*)d_in[3];  // tgt [B,3,N]
    float* out = (float*)d_out;

    float* part = (float*)d_ws;                 // NSETS*BN*NP*5 floats
    float* corr = part + PART_FLOATS;           // BN*3*NP floats

    dim3 g1(NP / ROWS, SPLITS, BN);             // 48 x 2 x 8
    k_attn<<<g1, 256, 0, stream>>>(qe, te, tgt, part);

    k_combine<<<(BN * NP + 255) / 256, 256, 0, stream>>>(part, corr);

    k_final<<<BN, 256, 0, stream>>>(src, corr, out);
}

// Round 2
// 139.181 us; speedup vs baseline: 2.3344x; 2.3344x over previous
//
#include <hip/hip_runtime.h>
#include <hip/hip_bf16.h>
#include <math.h>

#define BN 8
#define DEMB 128
#define NP 3072
#define MSPLIT 4
#define MRANGE (NP / MSPLIT)   // 768 m per block
#define NBLK 128               // n per block
#define NWAVE 32               // n per wave
#define NSETS MSPLIT

#define QT_ELEMS ((size_t)BN * NP * DEMB)
#define PART_FLOATS ((size_t)NSETS * BN * NP * 5)

typedef __attribute__((ext_vector_type(8))) short short8;
typedef __attribute__((ext_vector_type(4))) float f32x4;

// ------------------------------------------------------------------
// k_prep: fp32 [b][d][n] -> bf16 [b][n][d] (transpose + convert), both tensors
// ------------------------------------------------------------------
__global__ __launch_bounds__(256) void k_prep(const float* __restrict__ qe,
                                              const float* __restrict__ te,
                                              ushort* __restrict__ qT,
                                              ushort* __restrict__ eT)
{
    const int bid   = blockIdx.x;          // 2 * 8 * 12 * 2 = 384
    const int t     = bid & 1;
    const int b     = (bid >> 1) & 7;
    const int nblk  = (bid >> 4) % 12;
    const int dhalf = bid / 192;

    const float* src = t ? te : qe;
    ushort*      dst = t ? eT : qT;

    const int n = nblk * 256 + threadIdx.x;
    const float* sp = src + (size_t)b * DEMB * NP + n;
    ushort*      dp = dst + ((size_t)b * NP + n) * DEMB;

    for (int oct = 0; oct < 8; ++oct) {
        const int d0 = dhalf * 64 + oct * 8;
        ushort u[8];
#pragma unroll
        for (int dd = 0; dd < 8; ++dd) {
            const float v = sp[(size_t)(d0 + dd) * NP];
            __hip_bfloat16 h = __float2bfloat16(v);
            u[dd] = *reinterpret_cast<ushort*>(&h);
        }
        *reinterpret_cast<uint4*>(dp + d0) = *reinterpret_cast<const uint4*>(u);
    }
}

// ------------------------------------------------------------------
// k_attn: MFMA flash attention, S^T orientation (rows=m, cols=n).
// A = e^T tile (m x k), B = q^T-as-B (k x n), both frag loads are 16B
// contiguous global loads from the [n][d] bf16 layout.
// ------------------------------------------------------------------
__global__ __launch_bounds__(256) void k_attn(const ushort* __restrict__ qT,
                                              const ushort* __restrict__ eT,
                                              const float* __restrict__ tgt,
                                              float* __restrict__ part)
{
    const int bid  = blockIdx.x;           // 768 = 8b * 24nblk * 4msplit
    const int b    = bid & 7;              // batch -> XCD pinning
    const int r    = bid >> 3;
    const int nblk = r % 24;
    const int ms   = r / 24;

    const int wid  = threadIdx.x >> 6;
    const int lane = threadIdx.x & 63;
    const int g    = lane >> 4;
    const int c16  = lane & 15;

    const int nw = nblk * NBLK + wid * NWAVE;
    const ushort* qb = qT + (size_t)b * NP * DEMB;
    const ushort* eb = eT + (size_t)b * NP * DEMB;
    const float*  tp = tgt + (size_t)b * 3 * NP;

    // B-frags (q), resident for the whole m-loop: 2 n-subtiles x 4 k-frags
    short8 bq[2][4];
#pragma unroll
    for (int ns = 0; ns < 2; ++ns)
#pragma unroll
        for (int kf = 0; kf < 4; ++kf)
            bq[ns][kf] = *(const short8*)(qb + (size_t)(nw + ns * 16 + c16) * DEMB
                                          + kf * 32 + g * 8);

    float o[2][3] = {{0.f, 0.f, 0.f}, {0.f, 0.f, 0.f}};
    float lrun[2] = {0.f, 0.f};
    float mrun[2] = {-3.0e38f, -3.0e38f};
    const float scale = 0.08838834764831845f;   // 1/sqrt(128)

    for (int mc = 0; mc < MRANGE / 64; ++mc) {
        const int m0 = ms * MRANGE + mc * 64;

        f32x4 s[4][2];
#pragma unroll
        for (int msub = 0; msub < 4; ++msub) {
            const ushort* ar = eb + (size_t)(m0 + msub * 16 + c16) * DEMB + g * 8;
            const short8 a0 = *(const short8*)(ar);
            const short8 a1 = *(const short8*)(ar + 32);
            const short8 a2 = *(const short8*)(ar + 64);
            const short8 a3 = *(const short8*)(ar + 96);
            f32x4 c0 = {0.f, 0.f, 0.f, 0.f};
            f32x4 c1 = {0.f, 0.f, 0.f, 0.f};
            c0 = __builtin_amdgcn_mfma_f32_16x16x32_bf16(a0, bq[0][0], c0, 0, 0, 0);
            c0 = __builtin_amdgcn_mfma_f32_16x16x32_bf16(a1, bq[0][1], c0, 0, 0, 0);
            c0 = __builtin_amdgcn_mfma_f32_16x16x32_bf16(a2, bq[0][2], c0, 0, 0, 0);
            c0 = __builtin_amdgcn_mfma_f32_16x16x32_bf16(a3, bq[0][3], c0, 0, 0, 0);
            c1 = __builtin_amdgcn_mfma_f32_16x16x32_bf16(a0, bq[1][0], c1, 0, 0, 0);
            c1 = __builtin_amdgcn_mfma_f32_16x16x32_bf16(a1, bq[1][1], c1, 0, 0, 0);
            c1 = __builtin_amdgcn_mfma_f32_16x16x32_bf16(a2, bq[1][2], c1, 0, 0, 0);
            c1 = __builtin_amdgcn_mfma_f32_16x16x32_bf16(a3, bq[1][3], c1, 0, 0, 0);
            s[msub][0] = c0;
            s[msub][1] = c1;
        }

        // online softmax over the 64-m chunk (per n-col; lane holds 16 m-rows)
        float mnew[2], cf[2];
#pragma unroll
        for (int ns = 0; ns < 2; ++ns) {
            float mxr = s[0][ns][0];
#pragma unroll
            for (int msub = 0; msub < 4; ++msub)
#pragma unroll
                for (int rr = 0; rr < 4; ++rr)
                    mxr = fmaxf(mxr, s[msub][ns][rr]);
            mxr = fmaxf(mxr, __shfl_xor(mxr, 16));
            mxr = fmaxf(mxr, __shfl_xor(mxr, 32));
            const float mn = fmaxf(mrun[ns], mxr * scale);
            cf[ns] = __expf(mrun[ns] - mn);
            mrun[ns] = mn;
            mnew[ns] = mn;
            lrun[ns] *= cf[ns];
            o[ns][0] *= cf[ns];
            o[ns][1] *= cf[ns];
            o[ns][2] *= cf[ns];
        }

#pragma unroll
        for (int msub = 0; msub < 4; ++msub) {
            const int mb = m0 + msub * 16 + g * 4;
            const f32x4 t0 = *(const f32x4*)(tp + 0 * NP + mb);
            const f32x4 t1 = *(const f32x4*)(tp + 1 * NP + mb);
            const f32x4 t2 = *(const f32x4*)(tp + 2 * NP + mb);
#pragma unroll
            for (int rr = 0; rr < 4; ++rr) {
#pragma unroll
                for (int ns = 0; ns < 2; ++ns) {
                    const float p = __expf(fmaf(s[msub][ns][rr], scale, -mnew[ns]));
                    lrun[ns] += p;
                    o[ns][0] = fmaf(p, t0[rr], o[ns][0]);
                    o[ns][1] = fmaf(p, t1[rr], o[ns][1]);
                    o[ns][2] = fmaf(p, t2[rr], o[ns][2]);
                }
            }
        }
        __syncthreads();   // keep 4 waves converged on the same e-chunk (L1 reuse)
    }

    // reduce partial (over the 4 lane-groups = m-rows) and write flash partials
#pragma unroll
    for (int ns = 0; ns < 2; ++ns) {
#pragma unroll
        for (int mask = 16; mask <= 32; mask <<= 1) {
            o[ns][0] += __shfl_xor(o[ns][0], mask);
            o[ns][1] += __shfl_xor(o[ns][1], mask);
            o[ns][2] += __shfl_xor(o[ns][2], mask);
            lrun[ns] += __shfl_xor(lrun[ns], mask);
        }
        if (g == 0) {
            const int n = nw + ns * 16 + c16;
            float* pp = part + (((size_t)ms * BN + b) * NP + n) * 5;
            pp[0] = o[ns][0];
            pp[1] = o[ns][1];
            pp[2] = o[ns][2];
            pp[3] = lrun[ns];
            pp[4] = mrun[ns];
        }
    }
}

// ------------------------------------------------------------------
// k_combine: merge flash partials -> src_corr [B][3][N]
// ------------------------------------------------------------------
__global__ __launch_bounds__(256) void k_combine(const float* __restrict__ part,
                                                 float* __restrict__ corr)
{
    const int idx = blockIdx.x * 256 + threadIdx.x;
    if (idx >= BN * NP) return;
    const int b = idx / NP;
    const int n = idx % NP;
    float M = -3.0e38f;
#pragma unroll
    for (int s = 0; s < NSETS; ++s)
        M = fmaxf(M, part[(((size_t)s * BN + b) * NP + n) * 5 + 4]);
    float L = 0.f, o0 = 0.f, o1 = 0.f, o2 = 0.f;
#pragma unroll
    for (int s = 0; s < NSETS; ++s) {
        const float* pp = part + (((size_t)s * BN + b) * NP + n) * 5;
        const float w = __expf(pp[4] - M);
        o0 += pp[0] * w; o1 += pp[1] * w; o2 += pp[2] * w; L += pp[3] * w;
    }
    const float inv = 1.f / L;
    corr[((size_t)b * 3 + 0) * NP + n] = o0 * inv;
    corr[((size_t)b * 3 + 1) * NP + n] = o1 * inv;
    corr[((size_t)b * 3 + 2) * NP + n] = o2 * inv;
}

// ------------------------------------------------------------------
// k_final: per-batch reduction + 3x3 SVD (fp64 Jacobi) + R, t, euler
// ------------------------------------------------------------------
__global__ __launch_bounds__(256) void k_final(const float* __restrict__ src,
                                               const float* __restrict__ corr,
                                               float* __restrict__ out)
{
    const int b = blockIdx.x;
    const float* sp = src  + (size_t)b * 3 * NP;
    const float* cp = corr + (size_t)b * 3 * NP;

    double acc[15];
#pragma unroll
    for (int v = 0; v < 15; ++v) acc[v] = 0.0;

    for (int n = threadIdx.x; n < NP; n += 256) {
        const double x0 = sp[n], x1 = sp[NP + n], x2 = sp[2 * NP + n];
        const double y0 = cp[n], y1 = cp[NP + n], y2 = cp[2 * NP + n];
        acc[0] += x0; acc[1] += x1; acc[2] += x2;
        acc[3] += y0; acc[4] += y1; acc[5] += y2;
        acc[6]  += x0 * y0; acc[7]  += x0 * y1; acc[8]  += x0 * y2;
        acc[9]  += x1 * y0; acc[10] += x1 * y1; acc[11] += x1 * y2;
        acc[12] += x2 * y0; acc[13] += x2 * y1; acc[14] += x2 * y2;
    }

    const int wid = threadIdx.x >> 6, lane = threadIdx.x & 63;
#pragma unroll
    for (int v = 0; v < 15; ++v)
#pragma unroll
        for (int mask = 32; mask >= 1; mask >>= 1)
            acc[v] += __shfl_xor(acc[v], mask);

    __shared__ double red[4][15];
    if (lane == 0) {
#pragma unroll
        for (int v = 0; v < 15; ++v) red[wid][v] = acc[v];
    }
    __syncthreads();
    if (threadIdx.x != 0) return;

    double t15[15];
#pragma unroll
    for (int v = 0; v < 15; ++v)
        t15[v] = red[0][v] + red[1][v] + red[2][v] + red[3][v];

    const double invN = 1.0 / NP;
    const double mx[3] = {t15[0] * invN, t15[1] * invN, t15[2] * invN};
    const double my[3] = {t15[3] * invN, t15[4] * invN, t15[5] * invN};
    double H[3][3];
#pragma unroll
    for (int i = 0; i < 3; ++i)
#pragma unroll
        for (int j = 0; j < 3; ++j)
            H[i][j] = t15[6 + i * 3 + j] - (double)NP * mx[i] * my[j];

    double A[3][3], V[3][3];
#pragma unroll
    for (int i = 0; i < 3; ++i)
#pragma unroll
        for (int j = 0; j < 3; ++j) {
            A[i][j] = H[0][i] * H[0][j] + H[1][i] * H[1][j] + H[2][i] * H[2][j];
            V[i][j] = (i == j) ? 1.0 : 0.0;
        }

    for (int sweep = 0; sweep < 30; ++sweep) {
        const int pqs[3][2] = {{0, 1}, {0, 2}, {1, 2}};
        for (int k = 0; k < 3; ++k) {
            const int p = pqs[k][0], q = pqs[k][1];
            const double apq = A[p][q];
            if (fabs(apq) < 1e-300) continue;
            const double theta = (A[q][q] - A[p][p]) / (2.0 * apq);
            const double tj = (theta >= 0 ? 1.0 : -1.0) /
                              (fabs(theta) + sqrt(theta * theta + 1.0));
            const double c = 1.0 / sqrt(tj * tj + 1.0);
            const double s = tj * c;
            for (int i = 0; i < 3; ++i) {
                const double aip = A[i][p], aiq = A[i][q];
                A[i][p] = c * aip - s * aiq;
                A[i][q] = s * aip + c * aiq;
            }
            for (int i = 0; i < 3; ++i) {
                const double api = A[p][i], aqi = A[q][i];
                A[p][i] = c * api - s * aqi;
                A[q][i] = s * api + c * aqi;
            }
            for (int i = 0; i < 3; ++i) {
                const double vip = V[i][p], viq = V[i][q];
                V[i][p] = c * vip - s * viq;
                V[i][q] = s * vip + c * viq;
            }
        }
    }

    double lam[3] = {A[0][0], A[1][1], A[2][2]};
    int ord[3] = {0, 1, 2};
    for (int i = 0; i < 2; ++i)
        for (int j = i + 1; j < 3; ++j)
            if (lam[ord[j]] > lam[ord[i]]) { int t = ord[i]; ord[i] = ord[j]; ord[j] = t; }

    double Vs[3][3], sv[3];
    for (int j = 0; j < 3; ++j) {
        sv[j] = sqrt(fmax(lam[ord[j]], 0.0));
        for (int i = 0; i < 3; ++i) Vs[i][j] = V[i][ord[j]];
    }
    double U[3][3];
    for (int j = 0; j < 3; ++j) {
        const double h0 = H[0][0] * Vs[0][j] + H[0][1] * Vs[1][j] + H[0][2] * Vs[2][j];
        const double h1 = H[1][0] * Vs[0][j] + H[1][1] * Vs[1][j] + H[1][2] * Vs[2][j];
        const double h2 = H[2][0] * Vs[0][j] + H[2][1] * Vs[1][j] + H[2][2] * Vs[2][j];
        const double inv = 1.0 / fmax(sv[j], 1e-300);
        U[0][j] = h0 * inv; U[1][j] = h1 * inv; U[2][j] = h2 * inv;
    }

    double R[3][3];
    for (int i = 0; i < 3; ++i)
        for (int j = 0; j < 3; ++j)
            R[i][j] = Vs[i][0] * U[j][0] + Vs[i][1] * U[j][1] + Vs[i][2] * U[j][2];
    const double det =
        R[0][0] * (R[1][1] * R[2][2] - R[1][2] * R[2][1]) -
        R[0][1] * (R[1][0] * R[2][2] - R[1][2] * R[2][0]) +
        R[0][2] * (R[1][0] * R[2][1] - R[1][1] * R[2][0]);
    if (det < 0.0) {
        Vs[0][2] = -Vs[0][2]; Vs[1][2] = -Vs[1][2]; Vs[2][2] = -Vs[2][2];
        for (int i = 0; i < 3; ++i)
            for (int j = 0; j < 3; ++j)
                R[i][j] = Vs[i][0] * U[j][0] + Vs[i][1] * U[j][1] + Vs[i][2] * U[j][2];
    }

    double tvec[3];
    for (int i = 0; i < 3; ++i)
        tvec[i] = -(R[i][0] * mx[0] + R[i][1] * mx[1] + R[i][2] * mx[2]) + my[i];

    const double ex = atan2(R[2][1], R[2][2]);
    const double syv = sqrt(R[0][0] * R[0][0] + R[1][0] * R[1][0]);
    const double ey = atan2(-R[2][0], syv);
    const double ez = atan2(R[1][0], R[0][0]);

    for (int i = 0; i < 3; ++i)
        for (int j = 0; j < 3; ++j)
            out[b * 9 + i * 3 + j] = (float)R[i][j];
    out[72 + b * 3 + 0] = (float)tvec[0];
    out[72 + b * 3 + 1] = (float)tvec[1];
    out[72 + b * 3 + 2] = (float)tvec[2];
    out[96 + b * 3 + 0] = (float)ex;
    out[96 + b * 3 + 1] = (float)ey;
    out[96 + b * 3 + 2] = (float)ez;
}

// ------------------------------------------------------------------
extern "C" void kernel_launch(void* const* d_in, const int* in_sizes, int n_in,
                              void* d_out, int out_size, void* d_ws, size_t ws_size,
                              hipStream_t stream) {
    const float* qe  = (const float*)d_in[0];  // src_embedding [B,128,N]
    const float* te  = (const float*)d_in[1];  // tgt_embedding [B,128,N]
    const float* src = (const float*)d_in[2];  // src [B,3,N]
    const float* tgt = (const float*)d_in[3];  // tgt [B,3,N]
    float* out = (float*)d_out;

    ushort* qT  = (ushort*)d_ws;                       // bf16 [b][n][d]
    ushort* eT  = qT + QT_ELEMS;                       // bf16 [b][m][d]
    float*  part = (float*)(eT + QT_ELEMS);            // NSETS*BN*NP*5
    float*  corr = part + PART_FLOATS;                 // BN*3*NP

    k_prep<<<384, 256, 0, stream>>>(qe, te, qT, eT);
    k_attn<<<768, 256, 0, stream>>>(qT, eT, tgt, part);
    k_combine<<<(BN * NP + 255) / 256, 256, 0, stream>>>(part, corr);
    k_final<<<8, 256, 0, stream>>>(src, corr, out);
}

// Round 3
// 116.141 us; speedup vs baseline: 2.7974x; 1.1984x over previous
//
#include <hip/hip_runtime.h>
#include <hip/hip_bf16.h>
#include <math.h>

#define BN 8
#define DEMB 128
#define NP 3072
#define MSPLIT 8
#define MRANGE (NP / MSPLIT)   // 384 m per block
#define NBLK 128               // n per block
#define NWAVE 32               // n per wave

#define QT_ELEMS ((size_t)BN * NP * DEMB)

typedef __attribute__((ext_vector_type(8))) short short8;
typedef __attribute__((ext_vector_type(4))) float f32x4;

__device__ inline float fast_exp2(float x) {
#if __has_builtin(__builtin_amdgcn_exp2f)
    return __builtin_amdgcn_exp2f(x);
#else
    return __expf(x * 0.6931471805599453f);
#endif
}

// ------------------------------------------------------------------
// k_prep: fp32 [b][d][n] -> bf16 [b][n][d], LDS-staged so global writes
// are coalesced (512B bursts). One wave transposes a 16n x 128d tile.
// ------------------------------------------------------------------
#define PSTRIDE 132   // LDS row stride (ushort elems) for 128 d + pad

__global__ __launch_bounds__(256) void k_prep(const float* __restrict__ qe,
                                              const float* __restrict__ te,
                                              ushort* __restrict__ qT,
                                              ushort* __restrict__ eT)
{
    __shared__ ushort lds[4][16 * PSTRIDE];

    const int bid = blockIdx.x;            // 2 * 8 * 48 = 768
    const int t   = bid & 1;
    const int b   = (bid >> 1) & 7;
    const int nb  = bid >> 4;              // 0..47

    const float* src = (t ? te : qe) + (size_t)b * DEMB * NP;
    ushort*      dst = (t ? eT : qT) + (size_t)b * NP * DEMB;

    const int w    = threadIdx.x >> 6;
    const int lane = threadIdx.x & 63;
    const int n0   = nb * 64 + w * 16;

    // read phase: 8 passes, each wave covers 16 d-rows x 16 n (float4/lane)
#pragma unroll
    for (int p = 0; p < 8; ++p) {
        const int d  = p * 16 + (lane >> 2);
        const int nn = (lane & 3) * 4;
        const f32x4 v = *(const f32x4*)(src + (size_t)d * NP + n0 + nn);
#pragma unroll
        for (int k = 0; k < 4; ++k) {
            __hip_bfloat16 h = __float2bfloat16(v[k]);
            lds[w][(nn + k) * PSTRIDE + d] = *reinterpret_cast<ushort*>(&h);
        }
    }
    __syncthreads();

    // write phase: 8 passes x 8B per lane -> 512B contiguous per wave-pass
#pragma unroll
    for (int q = 0; q < 8; ++q) {
        const int flat = q * 256 + lane * 4;   // elem index within 16x128 tile
        const int n = flat >> 7;
        const int d = flat & 127;
        uint2 vv;
        vv.x = *(const uint*)&lds[w][n * PSTRIDE + d];
        vv.y = *(const uint*)&lds[w][n * PSTRIDE + d + 2];
        *(uint2*)(dst + ((size_t)(n0 + n)) * DEMB + d) = vv;
    }
}

// ------------------------------------------------------------------
// k_attn: MFMA scores (S^T orientation: rows=m, cols=n) + raw-exp softmax
// numerator/denominator accumulation. No max tracking (scores ~ N(0,1),
// exp2 arg bounded well inside fp32 range). Partials: float4 per (ms,b,n).
// ------------------------------------------------------------------
__global__ __launch_bounds__(256) void k_attn(const ushort* __restrict__ qT,
                                              const ushort* __restrict__ eT,
                                              const float* __restrict__ tgt,
                                              float4* __restrict__ part)
{
    const int bid  = blockIdx.x;           // 1536 = 8b * 24nblk * 8ms
    const int b    = bid & 7;              // batch -> XCD pinning
    const int r    = bid >> 3;
    const int nblk = r % 24;
    const int ms   = r / 24;

    const int wid  = threadIdx.x >> 6;
    const int lane = threadIdx.x & 63;
    const int g    = lane >> 4;
    const int c16  = lane & 15;

    const int nw = nblk * NBLK + wid * NWAVE;
    const ushort* qb = qT + (size_t)b * NP * DEMB;
    const ushort* eb = eT + (size_t)b * NP * DEMB;
    const float*  tp = tgt + (size_t)b * 3 * NP;

    // B-frags (q), resident for the whole m-loop
    short8 bq[2][4];
#pragma unroll
    for (int ns = 0; ns < 2; ++ns)
#pragma unroll
        for (int kf = 0; kf < 4; ++kf)
            bq[ns][kf] = *(const short8*)(qb + (size_t)(nw + ns * 16 + c16) * DEMB
                                          + kf * 32 + g * 8);

    float o[2][4];   // o0,o1,o2,l
#pragma unroll
    for (int ns = 0; ns < 2; ++ns)
        o[ns][0] = o[ns][1] = o[ns][2] = o[ns][3] = 0.f;

    const float scale2 = 0.12752962736873462f;  // log2(e)/sqrt(128)

    for (int mc = 0; mc < MRANGE / 64; ++mc) {
        const int m0 = ms * MRANGE + mc * 64;

        f32x4 s[4][2];
#pragma unroll
        for (int msub = 0; msub < 4; ++msub) {
            const ushort* ar = eb + (size_t)(m0 + msub * 16 + c16) * DEMB + g * 8;
            const short8 a0 = *(const short8*)(ar);
            const short8 a1 = *(const short8*)(ar + 32);
            const short8 a2 = *(const short8*)(ar + 64);
            const short8 a3 = *(const short8*)(ar + 96);
            f32x4 c0 = {0.f, 0.f, 0.f, 0.f};
            f32x4 c1 = {0.f, 0.f, 0.f, 0.f};
            c0 = __builtin_amdgcn_mfma_f32_16x16x32_bf16(a0, bq[0][0], c0, 0, 0, 0);
            c0 = __builtin_amdgcn_mfma_f32_16x16x32_bf16(a1, bq[0][1], c0, 0, 0, 0);
            c0 = __builtin_amdgcn_mfma_f32_16x16x32_bf16(a2, bq[0][2], c0, 0, 0, 0);
            c0 = __builtin_amdgcn_mfma_f32_16x16x32_bf16(a3, bq[0][3], c0, 0, 0, 0);
            c1 = __builtin_amdgcn_mfma_f32_16x16x32_bf16(a0, bq[1][0], c1, 0, 0, 0);
            c1 = __builtin_amdgcn_mfma_f32_16x16x32_bf16(a1, bq[1][1], c1, 0, 0, 0);
            c1 = __builtin_amdgcn_mfma_f32_16x16x32_bf16(a2, bq[1][2], c1, 0, 0, 0);
            c1 = __builtin_amdgcn_mfma_f32_16x16x32_bf16(a3, bq[1][3], c1, 0, 0, 0);
            s[msub][0] = c0;
            s[msub][1] = c1;
        }

        // raw-exp accumulation (numerator + denominator), no max tracking
#pragma unroll
        for (int msub = 0; msub < 4; ++msub) {
            const int mb = m0 + msub * 16 + g * 4;
            const f32x4 t0 = *(const f32x4*)(tp + 0 * NP + mb);
            const f32x4 t1 = *(const f32x4*)(tp + 1 * NP + mb);
            const f32x4 t2 = *(const f32x4*)(tp + 2 * NP + mb);
#pragma unroll
            for (int rr = 0; rr < 4; ++rr) {
#pragma unroll
                for (int ns = 0; ns < 2; ++ns) {
                    const float p = fast_exp2(s[msub][ns][rr] * scale2);
                    o[ns][3] += p;
                    o[ns][0] = fmaf(p, t0[rr], o[ns][0]);
                    o[ns][1] = fmaf(p, t1[rr], o[ns][1]);
                    o[ns][2] = fmaf(p, t2[rr], o[ns][2]);
                }
            }
        }
    }

    // reduce over the 4 m-row lane groups, write float4 partial
#pragma unroll
    for (int ns = 0; ns < 2; ++ns) {
#pragma unroll
        for (int v = 0; v < 4; ++v) {
            o[ns][v] += __shfl_xor(o[ns][v], 16);
            o[ns][v] += __shfl_xor(o[ns][v], 32);
        }
        if (g == 0) {
            const int n = nw + ns * 16 + c16;
            float4 pv;
            pv.x = o[ns][0]; pv.y = o[ns][1]; pv.z = o[ns][2]; pv.w = o[ns][3];
            part[((size_t)ms * BN + b) * NP + n] = pv;
        }
    }
}

// ------------------------------------------------------------------
// k_final: fused combine + per-batch reduction + 3x3 SVD + R, t, euler
// ------------------------------------------------------------------
__global__ __launch_bounds__(256) void k_final(const float* __restrict__ src,
                                               const float4* __restrict__ part,
                                               float* __restrict__ out)
{
    const int b = blockIdx.x;
    const float* sp = src + (size_t)b * 3 * NP;

    double acc[15];
#pragma unroll
    for (int v = 0; v < 15; ++v) acc[v] = 0.0;

    for (int n = threadIdx.x; n < NP; n += 256) {
        float o0 = 0.f, o1 = 0.f, o2 = 0.f, l = 0.f;
#pragma unroll
        for (int s = 0; s < MSPLIT; ++s) {
            const float4 pp = part[((size_t)s * BN + b) * NP + n];
            o0 += pp.x; o1 += pp.y; o2 += pp.z; l += pp.w;
        }
        const double inv = 1.0 / (double)l;
        const double y0 = o0 * inv, y1 = o1 * inv, y2 = o2 * inv;
        const double x0 = sp[n], x1 = sp[NP + n], x2 = sp[2 * NP + n];
        acc[0] += x0; acc[1] += x1; acc[2] += x2;
        acc[3] += y0; acc[4] += y1; acc[5] += y2;
        acc[6]  += x0 * y0; acc[7]  += x0 * y1; acc[8]  += x0 * y2;
        acc[9]  += x1 * y0; acc[10] += x1 * y1; acc[11] += x1 * y2;
        acc[12] += x2 * y0; acc[13] += x2 * y1; acc[14] += x2 * y2;
    }

    const int wid = threadIdx.x >> 6, lane = threadIdx.x & 63;
#pragma unroll
    for (int v = 0; v < 15; ++v)
#pragma unroll
        for (int mask = 32; mask >= 1; mask >>= 1)
            acc[v] += __shfl_xor(acc[v], mask);

    __shared__ double red[4][15];
    if (lane == 0) {
#pragma unroll
        for (int v = 0; v < 15; ++v) red[wid][v] = acc[v];
    }
    __syncthreads();
    if (threadIdx.x != 0) return;

    double t15[15];
#pragma unroll
    for (int v = 0; v < 15; ++v)
        t15[v] = red[0][v] + red[1][v] + red[2][v] + red[3][v];

    const double invN = 1.0 / NP;
    const double mx[3] = {t15[0] * invN, t15[1] * invN, t15[2] * invN};
    const double my[3] = {t15[3] * invN, t15[4] * invN, t15[5] * invN};
    double H[3][3];
#pragma unroll
    for (int i = 0; i < 3; ++i)
#pragma unroll
        for (int j = 0; j < 3; ++j)
            H[i][j] = t15[6 + i * 3 + j] - (double)NP * mx[i] * my[j];

    // A = H^T H, Jacobi eigendecomposition -> V, lambda
    double A[3][3], V[3][3];
#pragma unroll
    for (int i = 0; i < 3; ++i)
#pragma unroll
        for (int j = 0; j < 3; ++j) {
            A[i][j] = H[0][i] * H[0][j] + H[1][i] * H[1][j] + H[2][i] * H[2][j];
            V[i][j] = (i == j) ? 1.0 : 0.0;
        }

    for (int sweep = 0; sweep < 12; ++sweep) {
        const int pqs[3][2] = {{0, 1}, {0, 2}, {1, 2}};
        for (int k = 0; k < 3; ++k) {
            const int p = pqs[k][0], q = pqs[k][1];
            const double apq = A[p][q];
            if (apq * apq <= 1e-24 * (A[p][p] * A[p][p] + A[q][q] * A[q][q]))
                continue;
            const double theta = (A[q][q] - A[p][p]) / (2.0 * apq);
            const double tj = (theta >= 0 ? 1.0 : -1.0) /
                              (fabs(theta) + sqrt(theta * theta + 1.0));
            const double c = 1.0 / sqrt(tj * tj + 1.0);
            const double s = tj * c;
            for (int i = 0; i < 3; ++i) {
                const double aip = A[i][p], aiq = A[i][q];
                A[i][p] = c * aip - s * aiq;
                A[i][q] = s * aip + c * aiq;
            }
            for (int i = 0; i < 3; ++i) {
                const double api = A[p][i], aqi = A[q][i];
                A[p][i] = c * api - s * aqi;
                A[q][i] = s * api + c * aqi;
            }
            for (int i = 0; i < 3; ++i) {
                const double vip = V[i][p], viq = V[i][q];
                V[i][p] = c * vip - s * viq;
                V[i][q] = s * vip + c * viq;
            }
        }
    }

    double lam[3] = {A[0][0], A[1][1], A[2][2]};
    int ord[3] = {0, 1, 2};
    for (int i = 0; i < 2; ++i)
        for (int j = i + 1; j < 3; ++j)
            if (lam[ord[j]] > lam[ord[i]]) { int t = ord[i]; ord[i] = ord[j]; ord[j] = t; }

    double Vs[3][3], sv[3];
    for (int j = 0; j < 3; ++j) {
        sv[j] = sqrt(fmax(lam[ord[j]], 0.0));
        for (int i = 0; i < 3; ++i) Vs[i][j] = V[i][ord[j]];
    }
    double U[3][3];
    for (int j = 0; j < 3; ++j) {
        const double h0 = H[0][0] * Vs[0][j] + H[0][1] * Vs[1][j] + H[0][2] * Vs[2][j];
        const double h1 = H[1][0] * Vs[0][j] + H[1][1] * Vs[1][j] + H[1][2] * Vs[2][j];
        const double h2 = H[2][0] * Vs[0][j] + H[2][1] * Vs[1][j] + H[2][2] * Vs[2][j];
        const double inv = 1.0 / fmax(sv[j], 1e-300);
        U[0][j] = h0 * inv; U[1][j] = h1 * inv; U[2][j] = h2 * inv;
    }

    double R[3][3];
    for (int i = 0; i < 3; ++i)
        for (int j = 0; j < 3; ++j)
            R[i][j] = Vs[i][0] * U[j][0] + Vs[i][1] * U[j][1] + Vs[i][2] * U[j][2];
    const double det =
        R[0][0] * (R[1][1] * R[2][2] - R[1][2] * R[2][1]) -
        R[0][1] * (R[1][0] * R[2][2] - R[1][2] * R[2][0]) +
        R[0][2] * (R[1][0] * R[2][1] - R[1][1] * R[2][0]);
    if (det < 0.0) {
        Vs[0][2] = -Vs[0][2]; Vs[1][2] = -Vs[1][2]; Vs[2][2] = -Vs[2][2];
        for (int i = 0; i < 3; ++i)
            for (int j = 0; j < 3; ++j)
                R[i][j] = Vs[i][0] * U[j][0] + Vs[i][1] * U[j][1] + Vs[i][2] * U[j][2];
    }

    double tvec[3];
    for (int i = 0; i < 3; ++i)
        tvec[i] = -(R[i][0] * mx[0] + R[i][1] * mx[1] + R[i][2] * mx[2]) + my[i];

    const double ex = atan2(R[2][1], R[2][2]);
    const double syv = sqrt(R[0][0] * R[0][0] + R[1][0] * R[1][0]);
    const double ey = atan2(-R[2][0], syv);
    const double ez = atan2(R[1][0], R[0][0]);

    for (int i = 0; i < 3; ++i)
        for (int j = 0; j < 3; ++j)
            out[b * 9 + i * 3 + j] = (float)R[i][j];
    out[72 + b * 3 + 0] = (float)tvec[0];
    out[72 + b * 3 + 1] = (float)tvec[1];
    out[72 + b * 3 + 2] = (float)tvec[2];
    out[96 + b * 3 + 0] = (float)ex;
    out[96 + b * 3 + 1] = (float)ey;
    out[96 + b * 3 + 2] = (float)ez;
}

// ------------------------------------------------------------------
extern "C" void kernel_launch(void* const* d_in, const int* in_sizes, int n_in,
                              void* d_out, int out_size, void* d_ws, size_t ws_size,
                              hipStream_t stream) {
    const float* qe  = (const float*)d_in[0];  // src_embedding [B,128,N]
    const float* te  = (const float*)d_in[1];  // tgt_embedding [B,128,N]
    const float* src = (const float*)d_in[2];  // src [B,3,N]
    const float* tgt = (const float*)d_in[3];  // tgt [B,3,N]
    float* out = (float*)d_out;

    ushort* qT   = (ushort*)d_ws;                    // bf16 [b][n][d] 6.3MB
    ushort* eT   = qT + QT_ELEMS;                    // bf16 [b][m][d] 6.3MB
    float4* part = (float4*)(eT + QT_ELEMS);         // MSPLIT*BN*NP float4

    k_prep<<<768, 256, 0, stream>>>(qe, te, qT, eT);
    k_attn<<<1536, 256, 0, stream>>>(qT, eT, tgt, part);
    k_final<<<BN, 256, 0, stream>>>(src, part, out);
}